// Round 8
// baseline (906.240 us; speedup 1.0000x reference)
//
#include <hip/hip_runtime.h>
#include <hip/hip_bf16.h>
#include <stdint.h>
#include <string.h>

// Problem constants
#define S_LEN 512
#define NBATCH 64
#define EDIM 128
#define HDIM 256
#define GDIM 1024  // 4*H

// int8 quantization for the scan GEMM (exact integer MFMA):
//   W_q = rint(W*1024) (|W|<=1/16 -> |W_q|<=64), h_q = rint(h*127),
//   gates = acc_i32 / (127*1024) + xg.
// xg is pre-scaled per-gate by k_g (-log2e for i/f/o, +2log2e for g) by the
// producers, and the dequant constant absorbs the same factor, so the scan's
// activations use exp2 directly.
#define WQ_SCALE 1024.0f
#define HQ_SCALE 127.0f
#define LOG2E 1.4426950408889634f
#define C_IFO (-1.1093545e-05f)  // -log2e / 130048
#define C_G (2.2187090e-05f)     // +2*log2e / 130048

#define NSCAN 16   // scan blocks 0..15 (dispatch-first -> CUs immediately)
#define NPROD 240  // producer blocks 16..255; total 256 = capacity-exact

typedef __attribute__((ext_vector_type(8))) short short8;   // 8 bf16 (4 VGPRs) MFMA frag
typedef __attribute__((ext_vector_type(4))) short short4v;  // 4 bf16
typedef __attribute__((ext_vector_type(4))) float float4v;  // MFMA acc
typedef __attribute__((ext_vector_type(4))) int int4v;      // 16B i8 operand / i32 acc

// Workspace layout (bytes)
#define OFF_WHH8 0u
#define SZ_WHH8 (256u * 64u * 16u)           // 256 KB: W_hh_f i8 A-frags (K=64 layout)
#define OFF_WIH (OFF_WHH8 + SZ_WHH8)
#define SZ_WIH (64u * 4u * 64u * 16u)        // 256 KB: W_ih_f bf16 frags
#define OFF_XG ((size_t)(OFF_WIH + SZ_WIH))
#define SZ_XG ((size_t)S_LEN * NBATCH * GDIM * 2)  // 67 MB: xg bf16 [t][b][1024], pre-scaled
#define OFF_HF (OFF_XG + SZ_XG)              // 64 KB: h_f final, fp32 [64][256]
#define OFF_FLAGS (OFF_HF + (size_t)NBATCH * HDIM * 4)  // 128 ints: per-t-chunk ready flags

__device__ __forceinline__ short f2bf(float f) {
    union { float f; unsigned u; } v;
    v.f = f;
    unsigned r = (v.u + 0x7fffu + ((v.u >> 16) & 1u)) >> 16;  // RNE
    return (short)r;
}
__device__ __forceinline__ float bf2f(short s) {
    union { unsigned u; float f; } v;
    v.u = ((unsigned)(unsigned short)s) << 16;
    return v.f;
}
__device__ __forceinline__ float sigm(float x) {
    float e = __expf(-x);                    // v_exp
    return __builtin_amdgcn_rcpf(1.0f + e);  // v_rcp
}
__device__ __forceinline__ float tanh_(float x) {
    float e = __expf(2.0f * x);              // overflow -> inf -> rcp 0 -> +1; underflow -> -1
    return 1.0f - 2.0f * __builtin_amdgcn_rcpf(e + 1.0f);
}

// ---------------------------------------------------------------------------
// Setup (one launch): W_hh -> i8 K=64 A-frags; W_ih -> bf16 MFMA A-frags;
// zero producer-consumer flags. blocks 0..63 = whh, 64..127 = wih, 128 = flags.
// ---------------------------------------------------------------------------
__global__ __launch_bounds__(256) void setup_kernel(const float* __restrict__ whh_src,
                                                    const float* __restrict__ wih_src,
                                                    char* __restrict__ whh_dst,
                                                    char* __restrict__ wih_dst,
                                                    int* __restrict__ flags) {
    int bx = blockIdx.x;
    int tid = threadIdx.x;
    if (bx < 64) {
        // W_hh fp32 [1024,256] -> i8 frags (x1024). frag f = tile*4+kc;
        // lane(ln,q) byte b = W[tile*16+ln][kc*64+q*16+b]*1024.
        int id = bx * 256 + tid;
        int lane = id & 63;
        int f = id >> 6;  // < 256
        int tile = f >> 2, kc = f & 3;
        int row = tile * 16 + (lane & 15);
        int k0 = kc * 64 + ((lane >> 4) * 16);
        const float* s = whh_src + (size_t)row * HDIM + k0;
        union { char b[16]; int4v v; } u;
#pragma unroll
        for (int b = 0; b < 16; ++b)
            u.b[b] = (char)(int)rintf(s[b] * WQ_SCALE);
        *(int4v*)(whh_dst + ((size_t)f * 64 + lane) * 16) = u.v;
    } else if (bx < 128) {
        // W_ih fp32 [1024,128] -> bf16 frags: lane(ln,q) holds
        // W[tile*16+ln][c*32+q*8+j], j=0..7.  frag f = tile*4+c, f < 256.
        int id = (bx - 64) * 256 + tid;
        int lane = id & 63;
        int f = id >> 6;
        int tile = f >> 2;
        int c = f & 3;
        int row = tile * 16 + (lane & 15);
        int k0 = c * 32 + ((lane >> 4) * 8);
        const float* s = wih_src + (size_t)row * EDIM + k0;
        short8 pack;
#pragma unroll
        for (int j = 0; j < 8; ++j) pack[j] = f2bf(s[j]);
        *(short8*)(wih_dst + ((size_t)f * 64 + lane) * 16) = pack;
    } else {
        if (tid < 128) flags[tid] = 0;
    }
}

// ---------------------------------------------------------------------------
// Fused kernel (v14): scan-first block ordering.
//   Blocks 0..15 (scan): v11 body byte-identical + acquire-poll of
//     flags[(t+1)>>2] before each xg prefetch (protocol HW-proven in v10).
//     Dispatched FIRST so the latency-critical blocks own CUs from t=0.
//   Blocks 16..255 (producers): grid-stride over 512 units (unit u:
//     4 timesteps t0=(u>>2)*4 x 16 batches g16=u&3), ascending t.
//     Release-add flags[u>>2] after each unit. Never wait -> deadlock-free.
//   256 blocks x 1024 thr: all resident immediately (<= capacity even at
//   2 blocks/CU packing). Chunk 0 produced ~10 us after launch; producers
//   finish all 128 chunks by ~100 us vs scan consuming chunk 120 at ~465 us.
// ---------------------------------------------------------------------------
#define HPAD 320
__global__ __launch_bounds__(1024, 4) void fused_kernel(const int* __restrict__ seq,
                                                        const float* __restrict__ emb,
                                                        const char* __restrict__ wih_frags,
                                                        const float* __restrict__ bias_f,
                                                        char* __restrict__ xg,
                                                        const char* __restrict__ whh8,
                                                        float* __restrict__ hf_out,
                                                        int* __restrict__ flags) {
    if (blockIdx.x >= NSCAN) {
        // ------------------- producers: input projection -------------------
        __shared__ __align__(16) short lx[4][16][136];  // bf16 x-tiles, +8 pad
        int tid = threadIdx.x;
        for (int u = blockIdx.x - NSCAN; u < 512; u += NPROD) {
            __syncthreads();  // protect lx reuse across units
            int t0 = (u >> 2) * 4;
            int g16 = u & 3;

            // stage x: 64 rows (4t x 16b), 16 threads/row, 8 elems each
            {
                int row = tid >> 4;
                int tt = row >> 4, m = row & 15;
                int k0 = (tid & 15) * 8;
                int v = seq[(t0 + tt) * NBATCH + g16 * 16 + m];
                const float* src = emb + (size_t)v * EDIM + k0;
                bool zero = (v == 0);
#pragma unroll
                for (int uu = 0; uu < 8; uu += 4) {
                    float4v f = *(const float4v*)(src + uu);
                    short4v pk;
#pragma unroll
                    for (int e = 0; e < 4; ++e) pk[e] = zero ? (short)0 : f2bf(f[e]);
                    *(short4v*)&lx[tt][m][k0 + uu] = pk;
                }
            }
            __syncthreads();

            int lane = tid & 63, w = tid >> 6;  // w = 0..15
            int ln = lane & 15, q = lane >> 4;

            short8 Bx[4][4];  // x^T B-frags [t][kchunk]
#pragma unroll
            for (int tt = 0; tt < 4; ++tt)
#pragma unroll
                for (int c = 0; c < 4; ++c)
                    Bx[tt][c] = *(const short8*)&lx[tt][ln][c * 32 + q * 8];

#pragma unroll
            for (int nt = 0; nt < 4; ++nt) {
                int tile = w * 4 + nt;
                // per-gate exp2 pre-scale: gate = tile>>4 (0..3 = i,f,g,o)
                float kg = ((tile >> 4) == 2) ? (2.0f * LOG2E) : (-LOG2E);
                short8 Aw[4];
#pragma unroll
                for (int c = 0; c < 4; ++c)
                    Aw[c] = *(const short8*)(wih_frags + (((size_t)tile * 4 + c) * 64 + lane) * 16);
                float4v b4 = *(const float4v*)(bias_f + tile * 16 + q * 4);
#pragma unroll
                for (int tt = 0; tt < 4; ++tt) {
                    float4v acc = b4;
#pragma unroll
                    for (int c = 0; c < 4; ++c)
                        acc = __builtin_amdgcn_mfma_f32_16x16x32_bf16(Aw[c], Bx[tt][c], acc, 0, 0, 0);
                    short4v pk;
#pragma unroll
                    for (int r = 0; r < 4; ++r) pk[r] = f2bf(acc[r] * kg);
                    size_t off = ((size_t)(t0 + tt) * NBATCH + g16 * 16 + ln) * GDIM + tile * 16 + q * 4;
                    *(short4v*)(xg + off * 2) = pk;
                }
            }
            __syncthreads();  // all stores in block drained (barrier waits vmcnt)
            if (tid == 0)
                __hip_atomic_fetch_add(&flags[u >> 2], 1, __ATOMIC_RELEASE,
                                       __HIP_MEMORY_SCOPE_AGENT);
        }
    } else {
        // ------------------- scan: v11 body + chunk polling -------------------
        __shared__ __align__(16) char hls[2][4][HPAD];  // h_q i8 [buf][batch][H]
        int tid = threadIdx.x;
        int lane = tid & 63, w = tid >> 6;  // w = 0..15: hidden j-tile
        int ln = lane & 15, q = lane >> 4;
        int bg = blockIdx.x;                // 16 batch groups of 4

        // W_hh i8 A-frags -> registers: tiles g*16+w, 4 kc each (64 regs)
        int4v Wfr[4][4];
#pragma unroll
        for (int g = 0; g < 4; ++g) {
            int tile = g * 16 + w;
#pragma unroll
            for (int kc = 0; kc < 4; ++kc)
                Wfr[g][kc] = *(const int4v*)(whh8 + (((size_t)(tile * 4 + kc)) * 64 + lane) * 16);
        }

        // zero both h buffers
        {
            int* hp = (int*)&hls[0][0][0];
            for (int i = tid; i < (2 * 4 * HPAD) / 4; i += 1024) hp[i] = 0;
        }

        const char* hrd = &hls[0][0][0];
        char* hwr = &hls[1][0][0];
        // broadcast read: lanes ln>=4 duplicate column ln&3 — REQUIRED for the
        // duplicate-C-column register gather below (and free: LDS broadcast).
        int hoff_rd = (ln & 3) * HPAD + q * 16;  // B-frag: 16B contig, +kc*64

        // element-phase ownership (lane-dense): all 64 lanes own one element
        int b = ln & 3;
        int rr = ln >> 2;
        int j = w * 16 + q * 4 + rr;
        int hoff_wr = b * HPAD + j;  // 1 i8 byte

        // select predicates for a[g][rr] (uniform per lane)
        bool r_lo = (rr & 1) != 0;
        bool r_hi = (rr & 2) != 0;

        float cst = 0.0f;

        // xg: lane's own (batch, j), pre-scaled; gate g at +g*512 bytes
        const char* xgp = xg + (((size_t)(bg * 4 + b) * GDIM + j) * 2);
        const size_t tstep = (size_t)NBATCH * GDIM * 2;  // 131072 B

        // producer-consumer wait: chunk ch ready when 4 producer units added.
        int ready_upto = 0;
#define WAIT_CHUNK(ch)                                                          \
        while (ready_upto <= (ch)) {                                            \
            int fv = __hip_atomic_load(&flags[ready_upto], __ATOMIC_ACQUIRE,    \
                                       __HIP_MEMORY_SCOPE_AGENT);               \
            if (fv >= 4) ++ready_upto;                                          \
            else __builtin_amdgcn_s_sleep(2);                                   \
        }

        WAIT_CHUNK(0);
        unsigned short xq[4];
#pragma unroll
        for (int g = 0; g < 4; ++g)
            xq[g] = *(const unsigned short*)(xgp + g * 512);

        __syncthreads();

        const int4v z4 = {0, 0, 0, 0};
        for (int t = 0; t < S_LEN; ++t) {
            // h(t-1) B-frags from read buffer: 4 x ds_read_b128 (2-way max)
            int4v Bh[4];
#pragma unroll
            for (int kc = 0; kc < 4; ++kc)
                Bh[kc] = *(const int4v*)(hrd + hoff_rd + kc * 64);

            // stash prefetched xg, then poll+issue next step's prefetch
            float xgf[4];
#pragma unroll
            for (int g = 0; g < 4; ++g) xgf[g] = bf2f((short)xq[g]);
            xgp += tstep;
            if (t != S_LEN - 1) {
                int ch = (t + 1) >> 2;
                WAIT_CHUNK(ch);  // steady state: ready_upto > ch, zero cost
#pragma unroll
                for (int g = 0; g < 4; ++g)
                    xq[g] = *(const unsigned short*)(xgp + g * 512);
            }

            // 4 independent i8 MFMA chains, chunk-major, zero C-operand on kc=0
            int4v a[4];
#pragma unroll
            for (int g = 0; g < 4; ++g)
                a[g] = __builtin_amdgcn_mfma_i32_16x16x64_i8(Wfr[g][0], Bh[0], z4, 0, 0, 0);
#pragma unroll
            for (int kc = 1; kc < 4; ++kc)
#pragma unroll
                for (int g = 0; g < 4; ++g)
                    a[g] = __builtin_amdgcn_mfma_i32_16x16x64_i8(Wfr[g][kc], Bh[kc], a[g], 0, 0, 0);

            // register gather: lane's element (b=ln&3, rr) is its own a[g][rr]
            // (C cols 4..15 duplicate 0..3 because B cols were broadcast).
            int gsel[4];
#pragma unroll
            for (int g = 0; g < 4; ++g) {
                int v01 = r_lo ? a[g][1] : a[g][0];
                int v23 = r_lo ? a[g][3] : a[g][2];
                gsel[g] = r_hi ? v23 : v01;
            }
            // dequant (log2e-folded) + add pre-scaled xg
            float s0 = fmaf((float)gsel[0], C_IFO, xgf[0]);  // i
            float s1 = fmaf((float)gsel[1], C_IFO, xgf[1]);  // f
            float s2 = fmaf((float)gsel[2], C_G, xgf[2]);    // g
            float s3 = fmaf((float)gsel[3], C_IFO, xgf[3]);  // o

            // exp2-based activations
            float iv = __builtin_amdgcn_rcpf(1.0f + exp2f(s0));
            float fv = __builtin_amdgcn_rcpf(1.0f + exp2f(s1));
            float gv = fmaf(-2.0f, __builtin_amdgcn_rcpf(1.0f + exp2f(s2)), 1.0f);
            float ov = __builtin_amdgcn_rcpf(1.0f + exp2f(s3));
            float cv = fmaf(fv, cst, iv * gv);
            cst = cv;
            float tc = fmaf(-2.0f, __builtin_amdgcn_rcpf(1.0f + exp2f(cv * (2.0f * LOG2E))), 1.0f);
            float hv = ov * tc;

            // h_q = rint(h*127) -> i8 byte into other buffer
            int hq = (int)rintf(hv * HQ_SCALE);
            hwr[hoff_wr] = (char)hq;

            if (t == S_LEN - 1)
                hf_out[((size_t)(bg * 4 + b)) * HDIM + j] = hv;

            const char* tr = hrd; hrd = hwr; hwr = (char*)tr;
            __syncthreads();
        }
#undef WAIT_CHUNK
    }
}

// ---------------------------------------------------------------------------
// Tail: backward cell at position S-1 (h0=c0=0 => W_hh_b unused) + output proj.
// One block per batch element; thread j handles hidden unit j.
// ---------------------------------------------------------------------------
__global__ __launch_bounds__(256) void tail_kernel(const int* __restrict__ seq,
                                                   const float* __restrict__ emb,
                                                   const float* __restrict__ wih_b,
                                                   const float* __restrict__ b_b,
                                                   const float* __restrict__ wout,
                                                   const float* __restrict__ b_out,
                                                   const float* __restrict__ hf,
                                                   float* __restrict__ out) {
    __shared__ float xs[EDIM];
    __shared__ float red[4];
    int b = blockIdx.x, tid = threadIdx.x;
    if (tid < EDIM) {
        int v = seq[(S_LEN - 1) * NBATCH + b];
        xs[tid] = (v == 0) ? 0.0f : emb[(size_t)v * EDIM + tid];
    }
    __syncthreads();

    int j = tid;  // 0..255 = hidden unit
    float si = b_b[j], sg = b_b[2 * HDIM + j], so = b_b[3 * HDIM + j];
    const float* wi = wih_b + (size_t)j * EDIM;
    const float* wg = wih_b + (size_t)(2 * HDIM + j) * EDIM;
    const float* wo = wih_b + (size_t)(3 * HDIM + j) * EDIM;
#pragma unroll 8
    for (int k = 0; k < EDIM; k += 4) {
        float4v x4 = *(const float4v*)&xs[k];
        float4v a = *(const float4v*)(wi + k);
        float4v c = *(const float4v*)(wg + k);
        float4v d = *(const float4v*)(wo + k);
#pragma unroll
        for (int e = 0; e < 4; ++e) {
            si += a[e] * x4[e];
            sg += c[e] * x4[e];
            so += d[e] * x4[e];
        }
    }
    float cc = sigm(si) * tanh_(sg);   // c = i*g   (f*c0 = 0)
    float hb = sigm(so) * tanh_(cc);   // h = o*tanh(c)
    float partial = hf[(size_t)b * HDIM + j] * wout[j] + hb * wout[HDIM + j];

    float val = partial;
#pragma unroll
    for (int off = 32; off > 0; off >>= 1) val += __shfl_down(val, off, 64);
    int lane = tid & 63, wv = tid >> 6;
    if (lane == 0) red[wv] = val;
    __syncthreads();
    if (tid == 0) out[b] = sigm(red[0] + red[1] + red[2] + red[3] + b_out[0]);
}

extern "C" void kernel_launch(void* const* d_in, const int* in_sizes, int n_in,
                              void* d_out, int out_size, void* d_ws, size_t ws_size,
                              hipStream_t stream) {
    const int* seq = (const int*)d_in[0];
    const float* emb = (const float*)d_in[1];
    const float* Wih_f = (const float*)d_in[2];
    const float* Whh_f = (const float*)d_in[3];
    const float* b_f = (const float*)d_in[4];
    const float* Wih_b = (const float*)d_in[5];
    // d_in[6] = W_hh_b: provably unused (backward scan's only needed output is its
    // step 0, where h0 = 0 so the recurrent term vanishes).
    const float* b_b = (const float*)d_in[7];
    const float* Wout = (const float*)d_in[8];
    const float* b_out = (const float*)d_in[9];
    float* out = (float*)d_out;
    char* ws = (char*)d_ws;
    int* flags = (int*)(ws + OFF_FLAGS);

    // 1) weight fragments + flag init (one launch)
    setup_kernel<<<dim3(129), 256, 0, stream>>>(Whh_f, Wih_f, ws + OFF_WHH8,
                                                ws + OFF_WIH, flags);
    // 2) fused: 16 scan blocks FIRST (own CUs from t=0) + 240 producer blocks
    //    (input projection, ascending t) — capacity-exact (256 x 1024 thr).
    fused_kernel<<<dim3(NSCAN + NPROD), 1024, 0, stream>>>(seq, emb, ws + OFF_WIH, b_f,
                                                           ws + OFF_XG, ws + OFF_WHH8,
                                                           (float*)(ws + OFF_HF), flags);
    // 3) backward single cell + output projection
    tail_kernel<<<dim3(NBATCH), 256, 0, stream>>>(seq, emb, Wih_b, b_b, Wout, b_out,
                                                  (const float*)(ws + OFF_HF), out);
}

// Round 9
// 620.637 us; speedup vs baseline: 1.4602x; 1.4602x over previous
//
#include <hip/hip_runtime.h>
#include <hip/hip_bf16.h>
#include <stdint.h>
#include <string.h>

// Problem constants
#define S_LEN 512
#define NBATCH 64
#define EDIM 128
#define HDIM 256
#define GDIM 1024  // 4*H

// int8 quantization for the scan GEMM (exact integer MFMA):
//   W_q = rint(W*1024) (|W|<=1/16 -> |W_q|<=64), h_q = rint(h*127),
//   gates = acc_i32 / (127*1024) + xg.
// xg is pre-scaled per-gate by k_g (-log2e for i/f/o, +2log2e for g) in
// input_proj, and the dequant constant absorbs the same factor, so the scan's
// activations use exp2 directly.
#define WQ_SCALE 1024.0f
#define HQ_SCALE 127.0f
#define LOG2E 1.4426950408889634f
#define C_IFO (-1.1093545e-05f)  // -log2e / 130048
#define C_G (2.2187090e-05f)     // +2*log2e / 130048

typedef __attribute__((ext_vector_type(8))) short short8;   // 8 bf16 (4 VGPRs) MFMA frag
typedef __attribute__((ext_vector_type(4))) short short4v;  // 4 bf16
typedef __attribute__((ext_vector_type(4))) float float4v;  // MFMA acc
typedef __attribute__((ext_vector_type(4))) int int4v;      // 16B i8 operand / i32 acc

// Workspace layout (bytes)
#define OFF_WHH8 0u
#define SZ_WHH8 (256u * 64u * 16u)           // 256 KB: W_hh_f i8 A-frags (K=64 layout)
#define OFF_WIH (OFF_WHH8 + SZ_WHH8)
#define SZ_WIH (64u * 4u * 64u * 16u)        // 256 KB: W_ih_f bf16 frags
#define OFF_XG ((size_t)(OFF_WIH + SZ_WIH))
#define SZ_XG ((size_t)S_LEN * NBATCH * GDIM * 2)  // 67 MB: xg bf16 [t][b][1024], pre-scaled
#define OFF_OPART (OFF_XG + SZ_XG)           // 256 B: out_partial[b] = hb.wout_hi + b_out

__device__ __forceinline__ short f2bf(float f) {
    union { float f; unsigned u; } v;
    v.f = f;
    unsigned r = (v.u + 0x7fffu + ((v.u >> 16) & 1u)) >> 16;  // RNE
    return (short)r;
}
__device__ __forceinline__ float bf2f(short s) {
    union { unsigned u; float f; } v;
    v.u = ((unsigned)(unsigned short)s) << 16;
    return v.f;
}
__device__ __forceinline__ float sigm(float x) {
    float e = __expf(-x);                    // v_exp
    return __builtin_amdgcn_rcpf(1.0f + e);  // v_rcp
}
__device__ __forceinline__ float tanh_(float x) {
    float e = __expf(2.0f * x);              // overflow -> inf -> rcp 0 -> +1; underflow -> -1
    return 1.0f - 2.0f * __builtin_amdgcn_rcpf(e + 1.0f);
}

// ---------------------------------------------------------------------------
// Setup (one launch, 192 blocks):
//   blocks   0..63 : W_hh fp32 -> i8 K=64 A-frags (x1024)
//   blocks  64..127: W_ih fp32 -> bf16 MFMA A-frags
//   blocks 128..191: backward cell at S-1 for batch (bx-128) — h0=c0=0 so
//                    W_hh_b drops out — reduced against wout_hi into
//                    out_partial[b] (includes b_out). Runs in parallel with
//                    the weight preps; removes the old tail_kernel launch.
// ---------------------------------------------------------------------------
__global__ __launch_bounds__(256) void setup_kernel(const float* __restrict__ whh_src,
                                                    const float* __restrict__ wih_src,
                                                    char* __restrict__ whh_dst,
                                                    char* __restrict__ wih_dst,
                                                    const int* __restrict__ seq,
                                                    const float* __restrict__ emb,
                                                    const float* __restrict__ wih_b,
                                                    const float* __restrict__ b_b,
                                                    const float* __restrict__ wout,
                                                    const float* __restrict__ b_out,
                                                    float* __restrict__ out_partial) {
    int bx = blockIdx.x;
    int tid = threadIdx.x;
    if (bx < 64) {
        // W_hh fp32 [1024,256] -> i8 frags (x1024). frag f = tile*4+kc;
        // lane(ln,q) byte b = W[tile*16+ln][kc*64+q*16+b]*1024.
        int id = bx * 256 + tid;
        int lane = id & 63;
        int f = id >> 6;  // < 256
        int tile = f >> 2, kc = f & 3;
        int row = tile * 16 + (lane & 15);
        int k0 = kc * 64 + ((lane >> 4) * 16);
        const float* s = whh_src + (size_t)row * HDIM + k0;
        union { char b[16]; int4v v; } u;
#pragma unroll
        for (int b = 0; b < 16; ++b)
            u.b[b] = (char)(int)rintf(s[b] * WQ_SCALE);
        *(int4v*)(whh_dst + ((size_t)f * 64 + lane) * 16) = u.v;
    } else if (bx < 128) {
        // W_ih fp32 [1024,128] -> bf16 frags: lane(ln,q) holds
        // W[tile*16+ln][c*32+q*8+j], j=0..7.  frag f = tile*4+c, f < 256.
        int id = (bx - 64) * 256 + tid;
        int lane = id & 63;
        int f = id >> 6;
        int tile = f >> 2;
        int c = f & 3;
        int row = tile * 16 + (lane & 15);
        int k0 = c * 32 + ((lane >> 4) * 8);
        const float* s = wih_src + (size_t)row * EDIM + k0;
        short8 pack;
#pragma unroll
        for (int j = 0; j < 8; ++j) pack[j] = f2bf(s[j]);
        *(short8*)(wih_dst + ((size_t)f * 64 + lane) * 16) = pack;
    } else {
        // backward single cell + partial output projection for batch b
        __shared__ float xs[EDIM];
        __shared__ float red[4];
        int b = bx - 128;
        if (tid < EDIM) {
            int v = seq[(S_LEN - 1) * NBATCH + b];
            xs[tid] = (v == 0) ? 0.0f : emb[(size_t)v * EDIM + tid];
        }
        __syncthreads();

        int j = tid;  // 0..255 = hidden unit
        float si = b_b[j], sg = b_b[2 * HDIM + j], so = b_b[3 * HDIM + j];
        const float* wi = wih_b + (size_t)j * EDIM;
        const float* wg = wih_b + (size_t)(2 * HDIM + j) * EDIM;
        const float* wo = wih_b + (size_t)(3 * HDIM + j) * EDIM;
#pragma unroll 8
        for (int k = 0; k < EDIM; k += 4) {
            float4v x4 = *(const float4v*)&xs[k];
            float4v a = *(const float4v*)(wi + k);
            float4v c = *(const float4v*)(wg + k);
            float4v d = *(const float4v*)(wo + k);
#pragma unroll
            for (int e = 0; e < 4; ++e) {
                si += a[e] * x4[e];
                sg += c[e] * x4[e];
                so += d[e] * x4[e];
            }
        }
        float cc = sigm(si) * tanh_(sg);   // c = i*g   (f*c0 = 0)
        float hb = sigm(so) * tanh_(cc);   // h = o*tanh(c)
        float val = hb * wout[HDIM + j];
#pragma unroll
        for (int off = 32; off > 0; off >>= 1) val += __shfl_down(val, off, 64);
        int lane = tid & 63, wv = tid >> 6;
        if (lane == 0) red[wv] = val;
        __syncthreads();
        if (tid == 0)
            out_partial[b] = red[0] + red[1] + red[2] + red[3] + b_out[0];
    }
}

// ---------------------------------------------------------------------------
// Input projection (transposed): xg[t][b][j] = (x[t,b,:] @ W_ih^T + b_f) * k_g
// where k_g = -log2e for gates i/f/o and +2*log2e for gate g (exp2 folding).
// A = W_ih frag, B = x^T frag -> C[m=j][n=batch].
// ---------------------------------------------------------------------------
__global__ __launch_bounds__(256) void input_proj(const int* __restrict__ seq,
                                                  const float* __restrict__ emb,
                                                  const char* __restrict__ wih_frags,
                                                  const float* __restrict__ bias,
                                                  char* __restrict__ xg) {
    __shared__ __align__(16) short lx[4][16][136];  // bf16 x-tiles, +8 pad
    int tid = threadIdx.x;
    int t0 = blockIdx.x * 4;
    int g = blockIdx.y;

    // stage x: 64 rows (4 t x 16 batch), 4 threads/row, 32 elems each
    {
        int row = tid >> 2;
        int tt = row >> 4, m = row & 15;
        int k0 = (tid & 3) * 32;
        int v = seq[(t0 + tt) * NBATCH + g * 16 + m];
        const float* src = emb + (size_t)v * EDIM + k0;
        bool zero = (v == 0);
#pragma unroll
        for (int u = 0; u < 32; u += 4) {
            float4v f = *(const float4v*)(src + u);
            short4v p;
#pragma unroll
            for (int e = 0; e < 4; ++e) p[e] = zero ? (short)0 : f2bf(f[e]);
            *(short4v*)&lx[tt][m][k0 + u] = p;
        }
    }
    __syncthreads();

    int lane = tid & 63, w = tid >> 6;
    int ln = lane & 15, q = lane >> 4;

    short8 Bx[4][4];  // x^T B-frags [t][kchunk]
#pragma unroll
    for (int tt = 0; tt < 4; ++tt)
#pragma unroll
        for (int c = 0; c < 4; ++c)
            Bx[tt][c] = *(const short8*)&lx[tt][ln][c * 32 + q * 8];

    for (int nt = 0; nt < 16; ++nt) {
        int tile = w * 16 + nt;
        // per-gate exp2 pre-scale: gate = tile>>4 (0..3 = i,f,g,o)
        float kg = ((tile >> 4) == 2) ? (2.0f * LOG2E) : (-LOG2E);
        short8 Aw[4];
#pragma unroll
        for (int c = 0; c < 4; ++c)
            Aw[c] = *(const short8*)(wih_frags + (((size_t)tile * 4 + c) * 64 + lane) * 16);
        float4v b4 = *(const float4v*)(bias + tile * 16 + q * 4);
#pragma unroll
        for (int tt = 0; tt < 4; ++tt) {
            float4v acc = b4;
#pragma unroll
            for (int c = 0; c < 4; ++c)
                acc = __builtin_amdgcn_mfma_f32_16x16x32_bf16(Aw[c], Bx[tt][c], acc, 0, 0, 0);
            short4v p;
#pragma unroll
            for (int r = 0; r < 4; ++r) p[r] = f2bf(acc[r] * kg);
            size_t off = ((size_t)(t0 + tt) * NBATCH + g * 16 + ln) * GDIM + tile * 16 + q * 4;
            *(short4v*)(xg + off * 2) = p;
        }
    }
}

// ---------------------------------------------------------------------------
// Forward LSTM scan, v15: 16 blocks x 4 batches x 16 waves (1024 thr).
//   = v11 (best verified scan: 494 us) + fused output epilogue:
//   at t = S-1, each lane computes hv*wout[j]; shfl-tree reduces the 16
//   same-batch lanes per wave, LDS reduces across 16 waves, and the block
//   writes out[b] = sigm(sum + out_partial[b]) directly (out_partial has the
//   backward-cell half + b_out, from setup). Removes the tail_kernel launch
//   and the hf_out global round-trip.
// ---------------------------------------------------------------------------
#define HPAD 320
__global__ __launch_bounds__(1024, 4) void lstm_scan(const char* __restrict__ whh8,
                                                     const char* __restrict__ xg,
                                                     const float* __restrict__ wout,
                                                     const float* __restrict__ out_partial,
                                                     float* __restrict__ out) {
    __shared__ __align__(16) char hls[2][4][HPAD];  // h_q i8 [buf][batch][H], pad to 320
    __shared__ float redz[64];                      // [wave][b] epilogue partials
    int tid = threadIdx.x;
    int lane = tid & 63, w = tid >> 6;  // w = 0..15: hidden j-tile
    int ln = lane & 15, q = lane >> 4;
    int bg = blockIdx.x;                // 16 batch groups of 4

    // W_hh i8 A-frags -> registers: tiles g*16+w, 4 kc each = 16 frags (64 regs)
    int4v Wfr[4][4];
#pragma unroll
    for (int g = 0; g < 4; ++g) {
        int tile = g * 16 + w;
#pragma unroll
        for (int kc = 0; kc < 4; ++kc)
            Wfr[g][kc] = *(const int4v*)(whh8 + (((size_t)(tile * 4 + kc)) * 64 + lane) * 16);
    }

    // zero both h buffers
    {
        int* hp = (int*)&hls[0][0][0];
        for (int i = tid; i < (2 * 4 * HPAD) / 4; i += 1024) hp[i] = 0;
    }

    const char* hrd = &hls[0][0][0];
    char* hwr = &hls[1][0][0];
    // broadcast read: lanes ln>=4 duplicate column ln&3 — REQUIRED for the
    // duplicate-C-column register gather below (and free: LDS broadcast).
    int hoff_rd = (ln & 3) * HPAD + q * 16;  // B-frag: 16 contiguous bytes, +kc*64

    // element-phase ownership (lane-dense): all 64 lanes own one element
    int b = ln & 3;
    int rr = ln >> 2;
    int j = w * 16 + q * 4 + rr;
    int hoff_wr = b * HPAD + j;  // 1 i8 byte

    // select predicates for a[g][rr] (uniform per lane, hoisted out of loop)
    bool r_lo = (rr & 1) != 0;
    bool r_hi = (rr & 2) != 0;

    float cst = 0.0f;
    float wj = wout[j];  // epilogue weight, loaded once

    // xg: lane's own (batch, j), pre-scaled; gate g at +g*256 elems = +512 bytes
    const char* xgp = xg + (((size_t)(bg * 4 + b) * GDIM + j) * 2);
    const size_t tstep = (size_t)NBATCH * GDIM * 2;  // 131072 B

    unsigned short xq[4];
#pragma unroll
    for (int g = 0; g < 4; ++g)
        xq[g] = *(const unsigned short*)(xgp + g * 512);

    __syncthreads();

    float hlast = 0.0f;
    const int4v z4 = {0, 0, 0, 0};
    for (int t = 0; t < S_LEN; ++t) {
        // h(t-1) B-frags from read buffer: 4 x ds_read_b128 (2-way max, free)
        int4v Bh[4];
#pragma unroll
        for (int kc = 0; kc < 4; ++kc)
            Bh[kc] = *(const int4v*)(hrd + hoff_rd + kc * 64);

        // stash prefetched xg (pre-scaled bf16), then issue next step's prefetch
        float xgf[4];
#pragma unroll
        for (int g = 0; g < 4; ++g) xgf[g] = bf2f((short)xq[g]);
        xgp += tstep;
        if (t != S_LEN - 1) {
#pragma unroll
            for (int g = 0; g < 4; ++g)
                xq[g] = *(const unsigned short*)(xgp + g * 512);
        }

        // 4 independent i8 MFMA chains, chunk-major, zero C-operand on kc=0
        int4v a[4];
#pragma unroll
        for (int g = 0; g < 4; ++g)
            a[g] = __builtin_amdgcn_mfma_i32_16x16x64_i8(Wfr[g][0], Bh[0], z4, 0, 0, 0);
#pragma unroll
        for (int kc = 1; kc < 4; ++kc)
#pragma unroll
            for (int g = 0; g < 4; ++g)
                a[g] = __builtin_amdgcn_mfma_i32_16x16x64_i8(Wfr[g][kc], Bh[kc], a[g], 0, 0, 0);

        // register gather: lane's element (b=ln&3, rr) is its own a[g][rr]
        // (C cols 4..15 duplicate 0..3 because B cols were broadcast).
        int gsel[4];
#pragma unroll
        for (int g = 0; g < 4; ++g) {
            int v01 = r_lo ? a[g][1] : a[g][0];
            int v23 = r_lo ? a[g][3] : a[g][2];
            gsel[g] = r_hi ? v23 : v01;
        }
        // dequant (log2e-folded) + add pre-scaled xg
        float s0 = fmaf((float)gsel[0], C_IFO, xgf[0]);  // i
        float s1 = fmaf((float)gsel[1], C_IFO, xgf[1]);  // f
        float s2 = fmaf((float)gsel[2], C_G, xgf[2]);    // g
        float s3 = fmaf((float)gsel[3], C_IFO, xgf[3]);  // o

        // exp2-based activations
        float iv = __builtin_amdgcn_rcpf(1.0f + exp2f(s0));
        float fv = __builtin_amdgcn_rcpf(1.0f + exp2f(s1));
        float gv = fmaf(-2.0f, __builtin_amdgcn_rcpf(1.0f + exp2f(s2)), 1.0f);
        float ov = __builtin_amdgcn_rcpf(1.0f + exp2f(s3));
        float cv = fmaf(fv, cst, iv * gv);
        cst = cv;
        float tc = fmaf(-2.0f, __builtin_amdgcn_rcpf(1.0f + exp2f(cv * (2.0f * LOG2E))), 1.0f);
        float hv = ov * tc;
        hlast = hv;

        // h_q = rint(h*127) -> i8 byte into other buffer
        int hq = (int)rintf(hv * HQ_SCALE);
        hwr[hoff_wr] = (char)hq;

        const char* tr = hrd; hrd = hwr; hwr = (char*)tr;
        __syncthreads();
    }

    // ---- fused output epilogue: out[b] = sigm(sum_j hlast*wout[j] + opart) ----
    float val = hlast * wj;
    // reduce the 16 lanes sharing this lane's b (lanes b, b+4, ..., b+60)
    val += __shfl_down(val, 32, 64);
    val += __shfl_down(val, 16, 64);
    val += __shfl_down(val, 8, 64);
    val += __shfl_down(val, 4, 64);
    if (lane < 4) redz[w * 4 + lane] = val;  // lane index == its b for lane<4
    __syncthreads();
    if (tid < 4) {
        float s = 0.0f;
#pragma unroll
        for (int wv = 0; wv < 16; ++wv) s += redz[wv * 4 + tid];
        out[bg * 4 + tid] = sigm(s + out_partial[bg * 4 + tid]);
    }
}

extern "C" void kernel_launch(void* const* d_in, const int* in_sizes, int n_in,
                              void* d_out, int out_size, void* d_ws, size_t ws_size,
                              hipStream_t stream) {
    const int* seq = (const int*)d_in[0];
    const float* emb = (const float*)d_in[1];
    const float* Wih_f = (const float*)d_in[2];
    const float* Whh_f = (const float*)d_in[3];
    const float* b_f = (const float*)d_in[4];
    const float* Wih_b = (const float*)d_in[5];
    // d_in[6] = W_hh_b: provably unused (backward scan's only needed output is its
    // step 0, where h0 = 0 so the recurrent term vanishes).
    const float* b_b = (const float*)d_in[7];
    const float* Wout = (const float*)d_in[8];
    const float* b_out = (const float*)d_in[9];
    float* out = (float*)d_out;
    char* ws = (char*)d_ws;
    float* opart = (float*)(ws + OFF_OPART);

    // 1) weight fragments + backward-cell partial (one launch, 192 parallel blocks)
    setup_kernel<<<dim3(192), 256, 0, stream>>>(Whh_f, Wih_f, ws + OFF_WHH8, ws + OFF_WIH,
                                                seq, emb, Wih_b, b_b, Wout, b_out, opart);
    // 2) forward input projections for all timesteps (xg bf16, per-gate exp2 pre-scale)
    input_proj<<<dim3(S_LEN / 4, 4), 256, 0, stream>>>(seq, emb, ws + OFF_WIH, b_f, ws + OFF_XG);
    // 3) sequential forward scan (16 batch groups of 4, 1 CU each, 16 waves)
    //    + fused output projection epilogue (writes out[] directly)
    lstm_scan<<<dim3(16), 1024, 0, stream>>>(ws + OFF_WHH8, ws + OFF_XG, Wout, opart, out);
}

// Round 10
// 617.912 us; speedup vs baseline: 1.4666x; 1.0044x over previous
//
#include <hip/hip_runtime.h>
#include <hip/hip_bf16.h>
#include <stdint.h>
#include <string.h>

// Problem constants
#define S_LEN 512
#define NBATCH 64
#define EDIM 128
#define HDIM 256
#define GDIM 1024  // 4*H

// int8 quantization for the scan GEMM (exact integer MFMA):
//   W_q = rint(W*1024) (|W|<=1/16 -> |W_q|<=64), h_q = rint(h*127),
//   gates = acc_i32 / (127*1024) + xg.
// xg is pre-scaled per-gate by k_g (-log2e for i/f/o, +2log2e for g) in
// input_proj, and the dequant constant absorbs the same factor, so the scan's
// activations use exp2 directly.
#define WQ_SCALE 1024.0f
#define HQ_SCALE 127.0f
#define LOG2E 1.4426950408889634f
#define C_IFO (-1.1093545e-05f)  // -log2e / 130048
#define C_G (2.2187090e-05f)     // +2*log2e / 130048

typedef __attribute__((ext_vector_type(8))) short short8;   // 8 bf16 (4 VGPRs) MFMA frag
typedef __attribute__((ext_vector_type(4))) short short4v;  // 4 bf16
typedef __attribute__((ext_vector_type(4))) float float4v;  // MFMA acc
typedef __attribute__((ext_vector_type(4))) int int4v;      // 16B i8 operand / i32 acc

// Workspace layout (bytes)
#define OFF_WHH8 0u
#define SZ_WHH8 (256u * 64u * 16u)           // 256 KB: W_hh_f i8 A-frags (K=64 layout)
#define OFF_WIH (OFF_WHH8 + SZ_WHH8)
#define SZ_WIH (64u * 4u * 64u * 16u)        // 256 KB: W_ih_f bf16 frags
#define OFF_XG ((size_t)(OFF_WIH + SZ_WIH))
#define SZ_XG ((size_t)S_LEN * NBATCH * GDIM * 2)  // 67 MB: xg bf16 [t][b][1024], pre-scaled
#define OFF_OPART (OFF_XG + SZ_XG)           // 256 B: out_partial[b] = hb.wout_hi + b_out

__device__ __forceinline__ short f2bf(float f) {
    union { float f; unsigned u; } v;
    v.f = f;
    unsigned r = (v.u + 0x7fffu + ((v.u >> 16) & 1u)) >> 16;  // RNE
    return (short)r;
}
__device__ __forceinline__ float bf2f(short s) {
    union { unsigned u; float f; } v;
    v.u = ((unsigned)(unsigned short)s) << 16;
    return v.f;
}
__device__ __forceinline__ float sigm(float x) {
    float e = __expf(-x);                    // v_exp
    return __builtin_amdgcn_rcpf(1.0f + e);  // v_rcp
}
__device__ __forceinline__ float tanh_(float x) {
    float e = __expf(2.0f * x);              // overflow -> inf -> rcp 0 -> +1; underflow -> -1
    return 1.0f - 2.0f * __builtin_amdgcn_rcpf(e + 1.0f);
}

// ---------------------------------------------------------------------------
// Setup (one launch, 192 blocks):
//   blocks   0..63 : W_hh fp32 -> i8 K=64 A-frags (x1024)
//   blocks  64..127: W_ih fp32 -> bf16 MFMA A-frags
//   blocks 128..191: backward cell at S-1 for batch (bx-128) — h0=c0=0 so
//                    W_hh_b drops out — reduced against wout_hi into
//                    out_partial[b] (includes b_out).
// ---------------------------------------------------------------------------
__global__ __launch_bounds__(256) void setup_kernel(const float* __restrict__ whh_src,
                                                    const float* __restrict__ wih_src,
                                                    char* __restrict__ whh_dst,
                                                    char* __restrict__ wih_dst,
                                                    const int* __restrict__ seq,
                                                    const float* __restrict__ emb,
                                                    const float* __restrict__ wih_b,
                                                    const float* __restrict__ b_b,
                                                    const float* __restrict__ wout,
                                                    const float* __restrict__ b_out,
                                                    float* __restrict__ out_partial) {
    int bx = blockIdx.x;
    int tid = threadIdx.x;
    if (bx < 64) {
        // W_hh fp32 [1024,256] -> i8 frags (x1024). frag f = tile*4+kc;
        // lane(ln,q) byte b = W[tile*16+ln][kc*64+q*16+b]*1024.
        int id = bx * 256 + tid;
        int lane = id & 63;
        int f = id >> 6;  // < 256
        int tile = f >> 2, kc = f & 3;
        int row = tile * 16 + (lane & 15);
        int k0 = kc * 64 + ((lane >> 4) * 16);
        const float* s = whh_src + (size_t)row * HDIM + k0;
        union { char b[16]; int4v v; } u;
#pragma unroll
        for (int b = 0; b < 16; ++b)
            u.b[b] = (char)(int)rintf(s[b] * WQ_SCALE);
        *(int4v*)(whh_dst + ((size_t)f * 64 + lane) * 16) = u.v;
    } else if (bx < 128) {
        // W_ih fp32 [1024,128] -> bf16 frags: lane(ln,q) holds
        // W[tile*16+ln][c*32+q*8+j], j=0..7.  frag f = tile*4+c, f < 256.
        int id = (bx - 64) * 256 + tid;
        int lane = id & 63;
        int f = id >> 6;
        int tile = f >> 2;
        int c = f & 3;
        int row = tile * 16 + (lane & 15);
        int k0 = c * 32 + ((lane >> 4) * 8);
        const float* s = wih_src + (size_t)row * EDIM + k0;
        short8 pack;
#pragma unroll
        for (int j = 0; j < 8; ++j) pack[j] = f2bf(s[j]);
        *(short8*)(wih_dst + ((size_t)f * 64 + lane) * 16) = pack;
    } else {
        // backward single cell + partial output projection for batch b
        __shared__ float xs[EDIM];
        __shared__ float red[4];
        int b = bx - 128;
        if (tid < EDIM) {
            int v = seq[(S_LEN - 1) * NBATCH + b];
            xs[tid] = (v == 0) ? 0.0f : emb[(size_t)v * EDIM + tid];
        }
        __syncthreads();

        int j = tid;  // 0..255 = hidden unit
        float si = b_b[j], sg = b_b[2 * HDIM + j], so = b_b[3 * HDIM + j];
        const float* wi = wih_b + (size_t)j * EDIM;
        const float* wg = wih_b + (size_t)(2 * HDIM + j) * EDIM;
        const float* wo = wih_b + (size_t)(3 * HDIM + j) * EDIM;
#pragma unroll 8
        for (int k = 0; k < EDIM; k += 4) {
            float4v x4 = *(const float4v*)&xs[k];
            float4v a = *(const float4v*)(wi + k);
            float4v c = *(const float4v*)(wg + k);
            float4v d = *(const float4v*)(wo + k);
#pragma unroll
            for (int e = 0; e < 4; ++e) {
                si += a[e] * x4[e];
                sg += c[e] * x4[e];
                so += d[e] * x4[e];
            }
        }
        float cc = sigm(si) * tanh_(sg);   // c = i*g   (f*c0 = 0)
        float hb = sigm(so) * tanh_(cc);   // h = o*tanh(c)
        float val = hb * wout[HDIM + j];
#pragma unroll
        for (int off = 32; off > 0; off >>= 1) val += __shfl_down(val, off, 64);
        int lane = tid & 63, wv = tid >> 6;
        if (lane == 0) red[wv] = val;
        __syncthreads();
        if (tid == 0)
            out_partial[b] = red[0] + red[1] + red[2] + red[3] + b_out[0];
    }
}

// ---------------------------------------------------------------------------
// Input projection v16: tile-split for 2x parallelism / latency hiding.
//   v15 post-mortem: 512 blocks (2/CU, 2 waves/SIMD) ran a long serial chain
//   of L2-latency frag loads -> ~5x over roofline. Split the 64 j-tiles into
//   halves: grid (128, 8), blockIdx.y = {tile-half 0..1} x {batch-group 0..3};
//   each block covers 32 tiles (wave w: 8 tiles). 1024 blocks = 4/CU,
//   8 waves/SIMD; per-block serial length halves; total frag traffic
//   unchanged (1024 x 128 KB = 134 MB).
//   xg[t][b][j] = (x[t,b,:] @ W_ih^T + b_f) * k_g; k_g = -log2e (i/f/o),
//   +2log2e (g) for exp2 folding in the scan.
// ---------------------------------------------------------------------------
__global__ __launch_bounds__(256) void input_proj(const int* __restrict__ seq,
                                                  const float* __restrict__ emb,
                                                  const char* __restrict__ wih_frags,
                                                  const float* __restrict__ bias,
                                                  char* __restrict__ xg) {
    __shared__ __align__(16) short lx[4][16][136];  // bf16 x-tiles, +8 pad
    int tid = threadIdx.x;
    int t0 = blockIdx.x * 4;
    int g = blockIdx.y & 3;        // batch group (16 batches)
    int th = blockIdx.y >> 2;      // tile half (0: tiles 0..31, 1: 32..63)

    // stage x: 64 rows (4 t x 16 batch), 4 threads/row, 32 elems each
    {
        int row = tid >> 2;
        int tt = row >> 4, m = row & 15;
        int k0 = (tid & 3) * 32;
        int v = seq[(t0 + tt) * NBATCH + g * 16 + m];
        const float* src = emb + (size_t)v * EDIM + k0;
        bool zero = (v == 0);
#pragma unroll
        for (int u = 0; u < 32; u += 4) {
            float4v f = *(const float4v*)(src + u);
            short4v p;
#pragma unroll
            for (int e = 0; e < 4; ++e) p[e] = zero ? (short)0 : f2bf(f[e]);
            *(short4v*)&lx[tt][m][k0 + u] = p;
        }
    }
    __syncthreads();

    int lane = tid & 63, w = tid >> 6;
    int ln = lane & 15, q = lane >> 4;

    short8 Bx[4][4];  // x^T B-frags [t][kchunk]
#pragma unroll
    for (int tt = 0; tt < 4; ++tt)
#pragma unroll
        for (int c = 0; c < 4; ++c)
            Bx[tt][c] = *(const short8*)&lx[tt][ln][c * 32 + q * 8];

#pragma unroll
    for (int nt = 0; nt < 8; ++nt) {
        int tile = th * 32 + w * 8 + nt;
        // per-gate exp2 pre-scale: gate = tile>>4 (0..3 = i,f,g,o)
        float kg = ((tile >> 4) == 2) ? (2.0f * LOG2E) : (-LOG2E);
        short8 Aw[4];
#pragma unroll
        for (int c = 0; c < 4; ++c)
            Aw[c] = *(const short8*)(wih_frags + (((size_t)tile * 4 + c) * 64 + lane) * 16);
        float4v b4 = *(const float4v*)(bias + tile * 16 + q * 4);
#pragma unroll
        for (int tt = 0; tt < 4; ++tt) {
            float4v acc = b4;
#pragma unroll
            for (int c = 0; c < 4; ++c)
                acc = __builtin_amdgcn_mfma_f32_16x16x32_bf16(Aw[c], Bx[tt][c], acc, 0, 0, 0);
            short4v p;
#pragma unroll
            for (int r = 0; r < 4; ++r) p[r] = f2bf(acc[r] * kg);
            size_t off = ((size_t)(t0 + tt) * NBATCH + g * 16 + ln) * GDIM + tile * 16 + q * 4;
            *(short4v*)(xg + off * 2) = p;
        }
    }
}

// ---------------------------------------------------------------------------
// Forward LSTM scan, v15 (unchanged, verified 492 us): 16 blocks x 4 batches
// x 16 waves, register-resident i8 W, broadcast Bh + duplicate-C register
// gather, exp2-folded activations, fused output epilogue.
// ---------------------------------------------------------------------------
#define HPAD 320
__global__ __launch_bounds__(1024, 4) void lstm_scan(const char* __restrict__ whh8,
                                                     const char* __restrict__ xg,
                                                     const float* __restrict__ wout,
                                                     const float* __restrict__ out_partial,
                                                     float* __restrict__ out) {
    __shared__ __align__(16) char hls[2][4][HPAD];  // h_q i8 [buf][batch][H], pad to 320
    __shared__ float redz[64];                      // [wave][b] epilogue partials
    int tid = threadIdx.x;
    int lane = tid & 63, w = tid >> 6;  // w = 0..15: hidden j-tile
    int ln = lane & 15, q = lane >> 4;
    int bg = blockIdx.x;                // 16 batch groups of 4

    // W_hh i8 A-frags -> registers: tiles g*16+w, 4 kc each = 16 frags (64 regs)
    int4v Wfr[4][4];
#pragma unroll
    for (int g = 0; g < 4; ++g) {
        int tile = g * 16 + w;
#pragma unroll
        for (int kc = 0; kc < 4; ++kc)
            Wfr[g][kc] = *(const int4v*)(whh8 + (((size_t)(tile * 4 + kc)) * 64 + lane) * 16);
    }

    // zero both h buffers
    {
        int* hp = (int*)&hls[0][0][0];
        for (int i = tid; i < (2 * 4 * HPAD) / 4; i += 1024) hp[i] = 0;
    }

    const char* hrd = &hls[0][0][0];
    char* hwr = &hls[1][0][0];
    // broadcast read: lanes ln>=4 duplicate column ln&3 — REQUIRED for the
    // duplicate-C-column register gather below (and free: LDS broadcast).
    int hoff_rd = (ln & 3) * HPAD + q * 16;  // B-frag: 16 contiguous bytes, +kc*64

    // element-phase ownership (lane-dense): all 64 lanes own one element
    int b = ln & 3;
    int rr = ln >> 2;
    int j = w * 16 + q * 4 + rr;
    int hoff_wr = b * HPAD + j;  // 1 i8 byte

    // select predicates for a[g][rr] (uniform per lane, hoisted out of loop)
    bool r_lo = (rr & 1) != 0;
    bool r_hi = (rr & 2) != 0;

    float cst = 0.0f;
    float wj = wout[j];  // epilogue weight, loaded once

    // xg: lane's own (batch, j), pre-scaled; gate g at +g*256 elems = +512 bytes
    const char* xgp = xg + (((size_t)(bg * 4 + b) * GDIM + j) * 2);
    const size_t tstep = (size_t)NBATCH * GDIM * 2;  // 131072 B

    unsigned short xq[4];
#pragma unroll
    for (int g = 0; g < 4; ++g)
        xq[g] = *(const unsigned short*)(xgp + g * 512);

    __syncthreads();

    float hlast = 0.0f;
    const int4v z4 = {0, 0, 0, 0};
    for (int t = 0; t < S_LEN; ++t) {
        // h(t-1) B-frags from read buffer: 4 x ds_read_b128 (2-way max, free)
        int4v Bh[4];
#pragma unroll
        for (int kc = 0; kc < 4; ++kc)
            Bh[kc] = *(const int4v*)(hrd + hoff_rd + kc * 64);

        // stash prefetched xg (pre-scaled bf16), then issue next step's prefetch
        float xgf[4];
#pragma unroll
        for (int g = 0; g < 4; ++g) xgf[g] = bf2f((short)xq[g]);
        xgp += tstep;
        if (t != S_LEN - 1) {
#pragma unroll
            for (int g = 0; g < 4; ++g)
                xq[g] = *(const unsigned short*)(xgp + g * 512);
        }

        // 4 independent i8 MFMA chains, chunk-major, zero C-operand on kc=0
        int4v a[4];
#pragma unroll
        for (int g = 0; g < 4; ++g)
            a[g] = __builtin_amdgcn_mfma_i32_16x16x64_i8(Wfr[g][0], Bh[0], z4, 0, 0, 0);
#pragma unroll
        for (int kc = 1; kc < 4; ++kc)
#pragma unroll
            for (int g = 0; g < 4; ++g)
                a[g] = __builtin_amdgcn_mfma_i32_16x16x64_i8(Wfr[g][kc], Bh[kc], a[g], 0, 0, 0);

        // register gather: lane's element (b=ln&3, rr) is its own a[g][rr]
        // (C cols 4..15 duplicate 0..3 because B cols were broadcast).
        int gsel[4];
#pragma unroll
        for (int g = 0; g < 4; ++g) {
            int v01 = r_lo ? a[g][1] : a[g][0];
            int v23 = r_lo ? a[g][3] : a[g][2];
            gsel[g] = r_hi ? v23 : v01;
        }
        // dequant (log2e-folded) + add pre-scaled xg
        float s0 = fmaf((float)gsel[0], C_IFO, xgf[0]);  // i
        float s1 = fmaf((float)gsel[1], C_IFO, xgf[1]);  // f
        float s2 = fmaf((float)gsel[2], C_G, xgf[2]);    // g
        float s3 = fmaf((float)gsel[3], C_IFO, xgf[3]);  // o

        // exp2-based activations
        float iv = __builtin_amdgcn_rcpf(1.0f + exp2f(s0));
        float fv = __builtin_amdgcn_rcpf(1.0f + exp2f(s1));
        float gv = fmaf(-2.0f, __builtin_amdgcn_rcpf(1.0f + exp2f(s2)), 1.0f);
        float ov = __builtin_amdgcn_rcpf(1.0f + exp2f(s3));
        float cv = fmaf(fv, cst, iv * gv);
        cst = cv;
        float tc = fmaf(-2.0f, __builtin_amdgcn_rcpf(1.0f + exp2f(cv * (2.0f * LOG2E))), 1.0f);
        float hv = ov * tc;
        hlast = hv;

        // h_q = rint(h*127) -> i8 byte into other buffer
        int hq = (int)rintf(hv * HQ_SCALE);
        hwr[hoff_wr] = (char)hq;

        const char* tr = hrd; hrd = hwr; hwr = (char*)tr;
        __syncthreads();
    }

    // ---- fused output epilogue: out[b] = sigm(sum_j hlast*wout[j] + opart) ----
    float val = hlast * wj;
    // reduce the 16 lanes sharing this lane's b (lanes b, b+4, ..., b+60)
    val += __shfl_down(val, 32, 64);
    val += __shfl_down(val, 16, 64);
    val += __shfl_down(val, 8, 64);
    val += __shfl_down(val, 4, 64);
    if (lane < 4) redz[w * 4 + lane] = val;  // lane index == its b for lane<4
    __syncthreads();
    if (tid < 4) {
        float s = 0.0f;
#pragma unroll
        for (int wv = 0; wv < 16; ++wv) s += redz[wv * 4 + tid];
        out[bg * 4 + tid] = sigm(s + out_partial[bg * 4 + tid]);
    }
}

extern "C" void kernel_launch(void* const* d_in, const int* in_sizes, int n_in,
                              void* d_out, int out_size, void* d_ws, size_t ws_size,
                              hipStream_t stream) {
    const int* seq = (const int*)d_in[0];
    const float* emb = (const float*)d_in[1];
    const float* Wih_f = (const float*)d_in[2];
    const float* Whh_f = (const float*)d_in[3];
    const float* b_f = (const float*)d_in[4];
    const float* Wih_b = (const float*)d_in[5];
    // d_in[6] = W_hh_b: provably unused (backward scan's only needed output is its
    // step 0, where h0 = 0 so the recurrent term vanishes).
    const float* b_b = (const float*)d_in[7];
    const float* Wout = (const float*)d_in[8];
    const float* b_out = (const float*)d_in[9];
    float* out = (float*)d_out;
    char* ws = (char*)d_ws;
    float* opart = (float*)(ws + OFF_OPART);

    // 1) weight fragments + backward-cell partial (one launch, 192 parallel blocks)
    setup_kernel<<<dim3(192), 256, 0, stream>>>(Whh_f, Wih_f, ws + OFF_WHH8, ws + OFF_WIH,
                                                seq, emb, Wih_b, b_b, Wout, b_out, opart);
    // 2) forward input projections, tile-split: 1024 blocks (4/CU) for latency hiding
    input_proj<<<dim3(S_LEN / 4, 8), 256, 0, stream>>>(seq, emb, ws + OFF_WIH, b_f, ws + OFF_XG);
    // 3) sequential forward scan (16 batch groups of 4, 1 CU each, 16 waves)
    //    + fused output projection epilogue (writes out[] directly)
    lstm_scan<<<dim3(16), 1024, 0, stream>>>(ws + OFF_WHH8, ws + OFF_XG, Wout, opart, out);
}